// Round 2
// baseline (564.108 us; speedup 1.0000x reference)
//
#include <hip/hip_runtime.h>
#include <math.h>

#define BATCH 2048
#define NBAS 103
#define OUTR 243     // real output width of hidden layers
#define OUTP 256     // padded output width

// ---------------- basis precompute: per (b,i) -> 4 weights + row offset ----------------
// u = (x - g0)/H with g0=-0.56, H=0.02. Interval j=floor(u); nonzero basis n=j-3..j
// clipped to [0,102]. Weights are the uniform cubic B-spline polynomials in t=u-j.
template <int IN>
__global__ __launch_bounds__(256) void basis_kernel(
    const float* __restrict__ xin, int xstride,
    float4* __restrict__ wbuf, int* __restrict__ obuf)
{
    int e = blockIdx.x * 256 + threadIdx.x;
    if (e >= BATCH * IN) return;
    int b = e / IN, i = e - b * IN;
    float x = xin[(size_t)b * xstride + i];
    float u = (x + 0.56f) * 50.0f;
    bool inr = (u >= 0.0f) && (u < 106.0f);
    float fj = floorf(u);
    float t = u - fj;
    int j = (int)fj;
    j = j < -1 ? -1 : (j > 106 ? 106 : j);
    float omt = 1.0f - t;
    float t2 = t * t, t3 = t2 * t;
    float w[4];
    w[0] = omt * omt * omt * (1.0f / 6.0f);
    w[1] = (3.0f * t3 - 6.0f * t2 + 4.0f) * (1.0f / 6.0f);
    w[2] = (-3.0f * t3 + 3.0f * t2 + 3.0f * t + 1.0f) * (1.0f / 6.0f);
    w[3] = t3 * (1.0f / 6.0f);
    int idx = j - 3;                       // first basis index n
    int idxc = idx < 0 ? 0 : (idx > 99 ? 99 : idx);   // clamp so idxc+3 <= 102
    int d = idx - idxc;                    // nonzero only at edges
    float4 wa;
    float* wap = &wa.x;
    #pragma unroll
    for (int m = 0; m < 4; ++m) {          // weight for row idxc+m is w[(idxc+m)-idx]
        int s = m - d;
        wap[m] = (inr && s >= 0 && s < 4) ? w[s] : 0.0f;
    }
    wbuf[e] = wa;
    obuf[e] = (i * NBAS + idxc) << 8;      // premultiplied by padded row stride 256
}

// ---------------- weight transpose: sw[o][r] -> swT[r][o], o padded to 256 ----------------
__global__ __launch_bounds__(256) void transpose_kernel(
    const float* __restrict__ src, float* __restrict__ dst, int O, int K)
{
    __shared__ float tile[32][33];
    int k0 = blockIdx.x * 32, o0 = blockIdx.y * 32;
    int tx = threadIdx.x & 31;
    int ty = threadIdx.x >> 5;     // 0..7
    #pragma unroll
    for (int r = ty; r < 32; r += 8) {
        int o = o0 + r, k = k0 + tx;
        if (o < O && k < K) tile[r][tx] = src[(size_t)o * K + k];
    }
    __syncthreads();
    #pragma unroll
    for (int r = ty; r < 32; r += 8) {
        int k = k0 + r, o = o0 + tx;
        if (k < K && o < O) dst[(size_t)k * OUTP + o] = tile[tx][r];
    }
}

__device__ __forceinline__ void fma4(float4& acc, float s, const float4& r) {
    acc.x = fmaf(s, r.x, acc.x);
    acc.y = fmaf(s, r.y, acc.y);
    acc.z = fmaf(s, r.z, acc.z);
    acc.w = fmaf(s, r.w, acc.w);
}

// ---------------- fused KAN layer (spline path + residual + optional base path) ----------------
// Block = 256 threads (4 waves). Wave handles 2 batch rows; lane covers o = lane*4..lane*4+3.
// grid = (BATCH/8, 2): blockIdx.y splits the i (K) range; partials combined via atomicAdd
// into a zeroed, 256-padded output.
template <int IN, bool RES>
__global__ __launch_bounds__(256) void layer_kernel(
    const float* __restrict__ swT,
    const float4* __restrict__ wbuf, const int* __restrict__ obuf,
    const float* __restrict__ h_in, int hstride,
    const float* __restrict__ bw,
    const float* __restrict__ wbp, const float* __restrict__ wsp,
    float* __restrict__ out)
{
    const int tid = threadIdx.x;
    const int lane = tid & 63;
    const int wave = tid >> 6;
    const int b0 = __builtin_amdgcn_readfirstlane(blockIdx.x * 8 + wave * 2);
    const int IH = (IN + 1) / 2;
    const int i0 = blockIdx.y ? IH : 0;
    const int i1 = blockIdx.y ? IN : IH;
    const float* colbase = swT + lane * 4;
    float4 acc0 = make_float4(0.f, 0.f, 0.f, 0.f);
    float4 acc1 = make_float4(0.f, 0.f, 0.f, 0.f);
    const float4* w0p = wbuf + (size_t)b0 * IN;
    const float4* w1p = wbuf + (size_t)(b0 + 1) * IN;
    const int* o0p = obuf + (size_t)b0 * IN;
    const int* o1p = obuf + (size_t)(b0 + 1) * IN;
    #pragma unroll 2
    for (int i = i0; i < i1; ++i) {
        float4 w0 = w0p[i]; int off0 = o0p[i];
        float4 w1 = w1p[i]; int off1 = o1p[i];
        const float* p0 = colbase + off0;
        const float* p1 = colbase + off1;
        float4 a0 = *(const float4*)(p0);
        float4 a1 = *(const float4*)(p0 + OUTP);
        float4 a2 = *(const float4*)(p0 + 2 * OUTP);
        float4 a3 = *(const float4*)(p0 + 3 * OUTP);
        float4 c0 = *(const float4*)(p1);
        float4 c1 = *(const float4*)(p1 + OUTP);
        float4 c2 = *(const float4*)(p1 + 2 * OUTP);
        float4 c3 = *(const float4*)(p1 + 3 * OUTP);
        fma4(acc0, w0.x, a0); fma4(acc0, w0.y, a1); fma4(acc0, w0.z, a2); fma4(acc0, w0.w, a3);
        fma4(acc1, w1.x, c0); fma4(acc1, w1.y, c1); fma4(acc1, w1.z, c2); fma4(acc1, w1.w, c3);
    }
    float wsv = wsp[0];
    float wbv = wbp[0];
    float ac[2][4] = {{acc0.x, acc0.y, acc0.z, acc0.w}, {acc1.x, acc1.y, acc1.z, acc1.w}};
    #pragma unroll
    for (int bl = 0; bl < 2; ++bl) {
        int b = b0 + bl;
        #pragma unroll
        for (int c = 0; c < 4; ++c) {
            int o = lane * 4 + c;
            float v = wsv * ac[bl][c];
            if (RES && blockIdx.y == 0) v += h_in[(size_t)b * hstride + o];
            if (wbv != 0.0f && o < OUTR) {   // base path: never taken for given inputs (wb==0)
                float bs = 0.0f;
                for (int i = i0; i < i1; ++i) {
                    float xx = h_in[(size_t)b * hstride + i];
                    bs = fmaf(xx / (1.0f + expf(-xx)), bw[o * IN + i], bs);
                }
                v += wbv * bs;
            }
            unsafeAtomicAdd(&out[(size_t)b * OUTP + o], v);
        }
    }
}

// ---------------- final layer 243 -> 1 ----------------
__global__ __launch_bounds__(256) void final_kernel(
    const float* __restrict__ sw5,          // (243*103,) original layout
    const float4* __restrict__ wbuf, const int* __restrict__ obuf,
    const float* __restrict__ h, const float* __restrict__ bw5,
    const float* __restrict__ wbp, const float* __restrict__ wsp,
    float* __restrict__ out)
{
    int wave = threadIdx.x >> 6, lane = threadIdx.x & 63;
    int b = blockIdx.x * 4 + wave;
    float s = 0.0f;
    for (int i = lane; i < OUTR; i += 64) {
        float4 w = wbuf[(size_t)b * OUTR + i];
        int off = obuf[(size_t)b * OUTR + i] >> 8;
        const float* p = sw5 + off;
        s += w.x * p[0] + w.y * p[1] + w.z * p[2] + w.w * p[3];
    }
    #pragma unroll
    for (int d = 32; d; d >>= 1) s += __shfl_down(s, d, 64);
    if (lane == 0) {
        float v = wsp[0] * s;
        float wbv = wbp[0];
        if (wbv != 0.0f) {
            float bs = 0.0f;
            for (int i = 0; i < OUTR; ++i) {
                float xx = h[(size_t)b * OUTP + i];
                bs = fmaf(xx / (1.0f + expf(-xx)), bw5[i], bs);
            }
            v += wbv * bs;
        }
        out[b] = v;
    }
}

extern "C" void kernel_launch(void* const* d_in, const int* in_sizes, int n_in,
                              void* d_out, int out_size, void* d_ws, size_t ws_size,
                              hipStream_t stream)
{
    const float* x = (const float*)d_in[0];
    const float *bw[6], *sw[6], *wb[6], *ws[6];
    for (int l = 0; l < 6; ++l) {
        bw[l] = (const float*)d_in[1 + 4 * l];
        sw[l] = (const float*)d_in[2 + 4 * l];
        wb[l] = (const float*)d_in[3 + 4 * l];
        ws[l] = (const float*)d_in[4 + 4 * l];
    }
    // workspace layout (floats)
    float* base = (float*)d_ws;
    const size_t SWT_OFF  = 0;                       // 25029*256 = 6,407,424
    const size_t WBUF_OFF = 6407424;                 // 2048*243*4 = 1,990,656
    const size_t OBUF_OFF = 8398080;                 // 497,664
    const size_t HA_OFF   = 8895744;                 // 2048*256 = 524,288
    const size_t HB_OFF   = 9420032;                 // 524,288 -> end 9,944,320 floats
    if (ws_size < (size_t)9944320 * 4) return;
    float*  swT  = base + SWT_OFF;
    float4* wbuf = (float4*)(base + WBUF_OFF);
    int*    obuf = (int*)(base + OBUF_OFF);
    float*  hA   = base + HA_OFF;
    float*  hB   = base + HB_OFF;
    float*  outp = (float*)d_out;

    const size_t HBYTES = (size_t)BATCH * OUTP * 4;

    // ---- layer 0: 64 -> 243, no residual ----
    transpose_kernel<<<dim3(206, 8), 256, 0, stream>>>(sw[0], swT, OUTR, 64 * NBAS);
    basis_kernel<64><<<(BATCH * 64 + 255) / 256, 256, 0, stream>>>(x, 64, wbuf, obuf);
    hipMemsetAsync(hA, 0, HBYTES, stream);
    layer_kernel<64, false><<<dim3(BATCH / 8, 2), 256, 0, stream>>>(
        swT, wbuf, obuf, x, 64, bw[0], wb[0], ws[0], hA);

    // ---- layers 1..4: 243 -> 243, residual ----
    float* hin = hA; float* hout = hB;
    for (int l = 1; l <= 4; ++l) {
        transpose_kernel<<<dim3(783, 8), 256, 0, stream>>>(sw[l], swT, OUTR, OUTR * NBAS);
        basis_kernel<243><<<(BATCH * OUTR + 255) / 256, 256, 0, stream>>>(hin, OUTP, wbuf, obuf);
        hipMemsetAsync(hout, 0, HBYTES, stream);
        layer_kernel<243, true><<<dim3(BATCH / 8, 2), 256, 0, stream>>>(
            swT, wbuf, obuf, hin, OUTP, bw[l], wb[l], ws[l], hout);
        float* tmp = hin; hin = hout; hout = tmp;
    }

    // ---- layer 5: 243 -> 1, no residual ----
    basis_kernel<243><<<(BATCH * OUTR + 255) / 256, 256, 0, stream>>>(hin, OUTP, wbuf, obuf);
    final_kernel<<<BATCH / 4, 256, 0, stream>>>(sw[5], wbuf, obuf, hin, bw[5], wb[5], ws[5], outp);
}

// Round 3
// 563.933 us; speedup vs baseline: 1.0003x; 1.0003x over previous
//
#include <hip/hip_runtime.h>
#include <hip/hip_fp16.h>
#include <math.h>

#define BATCH 2048
#define NBAS 103
#define OUTR 243     // real output width of hidden layers
#define OUTP 256     // padded output width

// ---------------- basis precompute: per (b,i) -> 4 weights + row offset ----------------
// u = (x - g0)/H with g0=-0.56, H=0.02. Interval j=floor(u); nonzero basis n=j-3..j
// clipped to [0,102]. Weights are the uniform cubic B-spline polynomials in t=u-j.
template <int IN>
__global__ __launch_bounds__(256) void basis_kernel(
    const float* __restrict__ xin, int xstride,
    float4* __restrict__ wbuf, int* __restrict__ obuf)
{
    int e = blockIdx.x * 256 + threadIdx.x;
    if (e >= BATCH * IN) return;
    int b = e / IN, i = e - b * IN;
    float x = xin[(size_t)b * xstride + i];
    float u = (x + 0.56f) * 50.0f;
    bool inr = (u >= 0.0f) && (u < 106.0f);
    float fj = floorf(u);
    float t = u - fj;
    int j = (int)fj;
    j = j < -1 ? -1 : (j > 106 ? 106 : j);
    float omt = 1.0f - t;
    float t2 = t * t, t3 = t2 * t;
    float w[4];
    w[0] = omt * omt * omt * (1.0f / 6.0f);
    w[1] = (3.0f * t3 - 6.0f * t2 + 4.0f) * (1.0f / 6.0f);
    w[2] = (-3.0f * t3 + 3.0f * t2 + 3.0f * t + 1.0f) * (1.0f / 6.0f);
    w[3] = t3 * (1.0f / 6.0f);
    int idx = j - 3;                       // first basis index n
    int idxc = idx < 0 ? 0 : (idx > 99 ? 99 : idx);   // clamp so idxc+3 <= 102
    int d = idx - idxc;                    // nonzero only at edges
    float4 wa;
    float* wap = &wa.x;
    #pragma unroll
    for (int m = 0; m < 4; ++m) {          // weight for row idxc+m is w[(idxc+m)-idx]
        int s = m - d;
        wap[m] = (inr && s >= 0 && s < 4) ? w[s] : 0.0f;
    }
    wbuf[e] = wa;
    obuf[e] = (i * NBAS + idxc) << 8;      // element offset: row * 256 (row stride = 256)
}

// ---------------- weight transpose + fp16 convert: sw[o][r] -> swT[r][o] (o pad 256) ----
__global__ __launch_bounds__(256) void transpose_kernel(
    const float* __restrict__ src, __half* __restrict__ dst, int O, int K)
{
    __shared__ float tile[32][33];
    int k0 = blockIdx.x * 32, o0 = blockIdx.y * 32;
    int tx = threadIdx.x & 31;
    int ty = threadIdx.x >> 5;     // 0..7
    #pragma unroll
    for (int r = ty; r < 32; r += 8) {
        int o = o0 + r, k = k0 + tx;
        if (o < O && k < K) tile[r][tx] = src[(size_t)o * K + k];
    }
    __syncthreads();
    #pragma unroll
    for (int r = ty; r < 32; r += 8) {
        int k = k0 + r, o = o0 + tx;
        if (k < K && o < O) dst[(size_t)k * OUTP + o] = __float2half(tile[tx][r]);
    }
}

// ---------------- fused KAN layer (spline path + residual + optional base path) ----------------
// Block = 256 threads (4 waves). Wave handles ONE batch row. swT is fp16 with the 4 tap
// rows contiguous (512 B apart): one 16B/lane load covers 2 whole tap rows. Lanes 0-31
// accumulate taps {0,2}, lanes 32-63 taps {1,3}; combined via __shfl_xor(32) at the end.
// grid = (BATCH/4, 2): blockIdx.y splits the i range; partials via atomicAdd into zeroed out.
template <int IN, bool RES>
__global__ __launch_bounds__(256) void layer_kernel(
    const __half* __restrict__ swT,
    const float4* __restrict__ wbuf, const int* __restrict__ obuf,
    const float* __restrict__ h_in, int hstride,
    const float* __restrict__ bw,
    const float* __restrict__ wbp, const float* __restrict__ wsp,
    float* __restrict__ out)
{
    const int tid = threadIdx.x;
    const int lane = tid & 63;
    const int wave = tid >> 6;
    const int b = blockIdx.x * 4 + wave;
    const int half_id = lane >> 5;       // 0: taps {0,2}; 1: taps {1,3}
    const int o8 = (lane & 31) * 8;      // this lane's 8 output columns
    const int IH = IN / 2;
    const int i0 = blockIdx.y ? IH : 0;
    const int i1 = blockIdx.y ? IN : IH;
    float acc[8] = {0.f, 0.f, 0.f, 0.f, 0.f, 0.f, 0.f, 0.f};
    const float4* wp = wbuf + (size_t)b * IN;
    const int* op = obuf + (size_t)b * IN;
    #pragma unroll 4
    for (int i = i0; i < i1; ++i) {
        float4 w = wp[i];
        int off = op[i];                               // row*256 element offset
        const __half* p = swT + (size_t)off + lane * 8;
        float wA = half_id ? w.y : w.x;
        float wB = half_id ? w.w : w.z;
        uint4 ua = *(const uint4*)(p);                 // rows r0 / r0+1 (low/high half-wave)
        uint4 ub = *(const uint4*)(p + 512);           // rows r0+2 / r0+3
        const __half2* ha = (const __half2*)&ua;
        const __half2* hb = (const __half2*)&ub;
        #pragma unroll
        for (int q = 0; q < 4; ++q) {
            float2 fa = __half22float2(ha[q]);
            float2 fb = __half22float2(hb[q]);
            acc[2 * q]     = fmaf(wA, fa.x, acc[2 * q]);
            acc[2 * q + 1] = fmaf(wA, fa.y, acc[2 * q + 1]);
            acc[2 * q]     = fmaf(wB, fb.x, acc[2 * q]);
            acc[2 * q + 1] = fmaf(wB, fb.y, acc[2 * q + 1]);
        }
    }
    // combine the two half-wave partials (partner lane ^32 has the other two taps)
    #pragma unroll
    for (int q = 0; q < 8; ++q)
        acc[q] += __shfl_xor(acc[q], 32, 64);
    float wsv = wsp[0];
    float wbv = wbp[0];
    if (half_id == 0) {
        #pragma unroll
        for (int c = 0; c < 8; ++c) {
            int o = o8 + c;
            float v = wsv * acc[c];
            if (RES && blockIdx.y == 0) v += h_in[(size_t)b * hstride + o];
            if (wbv != 0.0f && o < OUTR) {   // base path: never taken for given inputs (wb==0)
                float bs = 0.0f;
                for (int i = i0; i < i1; ++i) {
                    float xx = h_in[(size_t)b * hstride + i];
                    bs = fmaf(xx / (1.0f + expf(-xx)), bw[o * IN + i], bs);
                }
                v += wbv * bs;
            }
            unsafeAtomicAdd(&out[(size_t)b * OUTP + o], v);
        }
    }
}

// ---------------- final layer 243 -> 1 ----------------
__global__ __launch_bounds__(256) void final_kernel(
    const float* __restrict__ sw5,          // (243*103,) original fp32 layout
    const float4* __restrict__ wbuf, const int* __restrict__ obuf,
    const float* __restrict__ h, const float* __restrict__ bw5,
    const float* __restrict__ wbp, const float* __restrict__ wsp,
    float* __restrict__ out)
{
    int wave = threadIdx.x >> 6, lane = threadIdx.x & 63;
    int b = blockIdx.x * 4 + wave;
    float s = 0.0f;
    for (int i = lane; i < OUTR; i += 64) {
        float4 w = wbuf[(size_t)b * OUTR + i];
        int off = obuf[(size_t)b * OUTR + i] >> 8;     // flat index i*103+idxc
        const float* p = sw5 + off;
        s += w.x * p[0] + w.y * p[1] + w.z * p[2] + w.w * p[3];
    }
    #pragma unroll
    for (int d = 32; d; d >>= 1) s += __shfl_down(s, d, 64);
    if (lane == 0) {
        float v = wsp[0] * s;
        float wbv = wbp[0];
        if (wbv != 0.0f) {
            float bs = 0.0f;
            for (int i = 0; i < OUTR; ++i) {
                float xx = h[(size_t)b * OUTP + i];
                bs = fmaf(xx / (1.0f + expf(-xx)), bw5[i], bs);
            }
            v += wbv * bs;
        }
        out[b] = v;
    }
}

extern "C" void kernel_launch(void* const* d_in, const int* in_sizes, int n_in,
                              void* d_out, int out_size, void* d_ws, size_t ws_size,
                              hipStream_t stream)
{
    const float* x = (const float*)d_in[0];
    const float *bw[6], *sw[6], *wb[6], *ws[6];
    for (int l = 0; l < 6; ++l) {
        bw[l] = (const float*)d_in[1 + 4 * l];
        sw[l] = (const float*)d_in[2 + 4 * l];
        wb[l] = (const float*)d_in[3 + 4 * l];
        ws[l] = (const float*)d_in[4 + 4 * l];
    }
    // workspace layout (byte offsets, all 256B-aligned)
    char* base = (char*)d_ws;
    const size_t SWT_B  = 0;                 // 25029*256*2  = 12,814,848
    const size_t WBUF_B = 12814848;          // 2048*243*16  =  7,962,624
    const size_t OBUF_B = 20777472;          // 2048*243*4   =  1,990,656
    const size_t HA_B   = 22768128;          // 2048*256*4   =  2,097,152
    const size_t HB_B   = 24865280;          //                2,097,152 -> end 26,962,432
    if (ws_size < (size_t)26962432) return;
    __half* swT  = (__half*)(base + SWT_B);
    float4* wbuf = (float4*)(base + WBUF_B);
    int*    obuf = (int*)(base + OBUF_B);
    float*  hA   = (float*)(base + HA_B);
    float*  hB   = (float*)(base + HB_B);
    float*  outp = (float*)d_out;

    const size_t HBYTES = (size_t)BATCH * OUTP * 4;

    // ---- layer 0: 64 -> 243, no residual ----
    transpose_kernel<<<dim3(206, 8), 256, 0, stream>>>(sw[0], swT, OUTR, 64 * NBAS);
    basis_kernel<64><<<(BATCH * 64 + 255) / 256, 256, 0, stream>>>(x, 64, wbuf, obuf);
    hipMemsetAsync(hA, 0, HBYTES, stream);
    layer_kernel<64, false><<<dim3(BATCH / 4, 2), 256, 0, stream>>>(
        swT, wbuf, obuf, x, 64, bw[0], wb[0], ws[0], hA);

    // ---- layers 1..4: 243 -> 243, residual ----
    float* hin = hA; float* hout = hB;
    for (int l = 1; l <= 4; ++l) {
        transpose_kernel<<<dim3(783, 8), 256, 0, stream>>>(sw[l], swT, OUTR, OUTR * NBAS);
        basis_kernel<243><<<(BATCH * OUTR + 255) / 256, 256, 0, stream>>>(hin, OUTP, wbuf, obuf);
        hipMemsetAsync(hout, 0, HBYTES, stream);
        layer_kernel<243, true><<<dim3(BATCH / 4, 2), 256, 0, stream>>>(
            swT, wbuf, obuf, hin, OUTP, bw[l], wb[l], ws[l], hout);
        float* tmp = hin; hin = hout; hout = tmp;
    }

    // ---- layer 5: 243 -> 1, no residual ----
    basis_kernel<243><<<(BATCH * OUTR + 255) / 256, 256, 0, stream>>>(hin, OUTP, wbuf, obuf);
    final_kernel<<<BATCH / 4, 256, 0, stream>>>(sw[5], wbuf, obuf, hin, bw[5], wb[5], ws[5], outp);
}

// Round 4
// 515.016 us; speedup vs baseline: 1.0953x; 1.0950x over previous
//
#include <hip/hip_runtime.h>
#include <hip/hip_fp16.h>
#include <math.h>

#define BATCH 2048
#define NBAS 103
#define NPAIR 102     // pair-rows per input feature: (r, r+1), r in [0,101]
#define OUTR 243      // real output width of hidden layers
#define OUTP 256      // padded output width

typedef _Float16 half2v __attribute__((ext_vector_type(2)));

__device__ __forceinline__ float dot2(unsigned a, unsigned b, float c) {
#if __has_builtin(__builtin_amdgcn_fdot2)
    return __builtin_amdgcn_fdot2(__builtin_bit_cast(half2v, a),
                                  __builtin_bit_cast(half2v, b), c, false);
#else
    __half2 ha = __builtin_bit_cast(__half2, a), hb = __builtin_bit_cast(__half2, b);
    c = fmaf(__low2float(ha), __low2float(hb), c);
    c = fmaf(__high2float(ha), __high2float(hb), c);
    return c;
#endif
}

// ---------------- basis precompute: per (b,i) -> meta {half2 w01, half2 w23, pairoff, flat}
// u = (x+0.56)/0.02. Interval j=floor(u); nonzero basis n=j-3..j clipped to [0,102].
// Uniform cubic B-spline weights in t=u-j.
template <int IN>
__global__ __launch_bounds__(256) void basis_kernel(
    const float* __restrict__ xin, int xstride, uint4* __restrict__ meta)
{
    int e = blockIdx.x * 256 + threadIdx.x;
    if (e >= BATCH * IN) return;
    int b = e / IN, i = e - b * IN;
    float x = xin[(size_t)b * xstride + i];
    float u = (x + 0.56f) * 50.0f;
    bool inr = (u >= 0.0f) && (u < 106.0f);
    float fj = floorf(u);
    float t = u - fj;
    int j = (int)fj;
    j = j < -1 ? -1 : (j > 106 ? 106 : j);
    float omt = 1.0f - t;
    float t2 = t * t, t3 = t2 * t;
    float w[4];
    w[0] = omt * omt * omt * (1.0f / 6.0f);
    w[1] = (3.0f * t3 - 6.0f * t2 + 4.0f) * (1.0f / 6.0f);
    w[2] = (-3.0f * t3 + 3.0f * t2 + 3.0f * t + 1.0f) * (1.0f / 6.0f);
    w[3] = t3 * (1.0f / 6.0f);
    int idx = j - 3;                       // first basis index n
    int idxc = idx < 0 ? 0 : (idx > 99 ? 99 : idx);   // clamp so idxc+3 <= 102
    int d = idx - idxc;                    // nonzero only at edges
    float wc[4];
    #pragma unroll
    for (int m = 0; m < 4; ++m) {          // weight for row idxc+m is w[(idxc+m)-idx]
        int s = m - d;
        wc[m] = (inr && s >= 0 && s < 4) ? w[s] : 0.0f;
    }
    __half2 w01 = __floats2half2_rn(wc[0], wc[1]);
    __half2 w23 = __floats2half2_rn(wc[2], wc[3]);
    uint4 m4;
    m4.x = __builtin_bit_cast(unsigned, w01);
    m4.y = __builtin_bit_cast(unsigned, w23);
    m4.z = (unsigned)((i * NPAIR + idxc) << 8);   // pair-row offset in half2/uint units
    m4.w = (unsigned)(i * NBAS + idxc);           // flat index for fp32 final layer
    meta[e] = m4;
}

// ---------------- pair-table build: sw[o][i][n] (fp32) -> pairT[i][r][o] = half2(v_r, v_{r+1})
// One block per input feature i. LDS-staged transpose; o>=243 zero-padded.
__global__ __launch_bounds__(256) void pairgen_kernel(
    const float* __restrict__ sw, int IN, unsigned* __restrict__ pairT)
{
    __shared__ __half tile[NBAS * OUTP];   // 103*256*2 = 52,736 B
    int i = blockIdx.x;
    int t = threadIdx.x;
    if (t < OUTR) {
        const float* p = sw + ((size_t)t * IN + i) * NBAS;
        #pragma unroll 4
        for (int n = 0; n < NBAS; ++n)
            tile[n * OUTP + t] = __float2half(p[n]);
    } else {
        for (int n = 0; n < NBAS; ++n)
            tile[n * OUTP + t] = __float2half(0.0f);
    }
    __syncthreads();
    unsigned* dst = pairT + (size_t)i * NPAIR * 256;
    for (int idx = t; idx < NPAIR * 256; idx += 256) {
        // idx = p*256 + o ; tile stride is also 256 so tile[idx] = value at (row p, col o)
        unsigned lo = __half_as_ushort(tile[idx]);
        unsigned hi = __half_as_ushort(tile[idx + 256]);
        dst[idx] = lo | (hi << 16);
    }
}

// ---------------- fused KAN layer (spline path + residual + optional base path) ----------------
// Block = 256 threads (4 waves); wave handles one batch row b, lane covers o = lane*4..lane*4+3.
// grid = (BATCH/4, 4): blockIdx.y is a 4-way split of the i range -> 8192 waves (8/SIMD).
// Per (b,i): one wave-uniform 16B meta load + two coalesced 1KB pair-row loads; 8 v_dot2/lane.
// Partials combined via atomicAdd into zeroed 256-padded output.
template <int IN, bool RES>
__global__ __launch_bounds__(256, 8) void layer_kernel(
    const unsigned* __restrict__ pairT, const uint4* __restrict__ meta,
    const float* __restrict__ h_in, int hstride,
    const float* __restrict__ bw,
    const float* __restrict__ wbp, const float* __restrict__ wsp,
    float* __restrict__ out)
{
    const int lane = threadIdx.x & 63;
    const int wave = __builtin_amdgcn_readfirstlane(threadIdx.x >> 6);
    const int b = blockIdx.x * 4 + wave;
    const int cy = blockIdx.y;
    const int i0 = (IN * cy) >> 2;
    const int i1 = (IN * (cy + 1)) >> 2;
    const uint4* mp = meta + (size_t)b * IN;
    float acc[4] = {0.f, 0.f, 0.f, 0.f};
    #pragma unroll 2
    for (int i = i0; i < i1; ++i) {
        uint4 m = mp[i];                               // wave-uniform
        const uint4* pA = (const uint4*)(pairT + m.z) + lane;
        uint4 ra = pA[0];                              // pair (r0, r0+1), this lane's 4 outputs
        uint4 rb = pA[128];                            // pair (r0+2, r0+3) (+2 rows = +512 uints)
        acc[0] = dot2(m.x, ra.x, acc[0]);
        acc[1] = dot2(m.x, ra.y, acc[1]);
        acc[2] = dot2(m.x, ra.z, acc[2]);
        acc[3] = dot2(m.x, ra.w, acc[3]);
        acc[0] = dot2(m.y, rb.x, acc[0]);
        acc[1] = dot2(m.y, rb.y, acc[1]);
        acc[2] = dot2(m.y, rb.z, acc[2]);
        acc[3] = dot2(m.y, rb.w, acc[3]);
    }
    float wsv = wsp[0];
    float wbv = wbp[0];
    #pragma unroll
    for (int c = 0; c < 4; ++c) {
        int o = lane * 4 + c;
        float v = wsv * acc[c];
        if (RES && cy == 0) v += h_in[(size_t)b * hstride + o];
        if (wbv != 0.0f && o < OUTR) {   // base path: never taken for given inputs (wb==0)
            float bs = 0.0f;
            for (int i = i0; i < i1; ++i) {
                float xx = h_in[(size_t)b * hstride + i];
                bs = fmaf(xx / (1.0f + expf(-xx)), bw[o * IN + i], bs);
            }
            v += wbv * bs;
        }
        unsafeAtomicAdd(&out[(size_t)b * OUTP + o], v);
    }
}

// ---------------- final layer 243 -> 1 ----------------
__global__ __launch_bounds__(256) void final_kernel(
    const float* __restrict__ sw5,          // (243*103,) original fp32 layout
    const uint4* __restrict__ meta,
    const float* __restrict__ h, const float* __restrict__ bw5,
    const float* __restrict__ wbp, const float* __restrict__ wsp,
    float* __restrict__ out)
{
    int wave = threadIdx.x >> 6, lane = threadIdx.x & 63;
    int b = blockIdx.x * 4 + wave;
    float s = 0.0f;
    for (int i = lane; i < OUTR; i += 64) {
        uint4 m = meta[(size_t)b * OUTR + i];
        __half2 w01 = __builtin_bit_cast(__half2, m.x);
        __half2 w23 = __builtin_bit_cast(__half2, m.y);
        const float* p = sw5 + m.w;
        s += __low2float(w01) * p[0] + __high2float(w01) * p[1]
           + __low2float(w23) * p[2] + __high2float(w23) * p[3];
    }
    #pragma unroll
    for (int d = 32; d; d >>= 1) s += __shfl_down(s, d, 64);
    if (lane == 0) {
        float v = wsp[0] * s;
        float wbv = wbp[0];
        if (wbv != 0.0f) {
            float bs = 0.0f;
            for (int i = 0; i < OUTR; ++i) {
                float xx = h[(size_t)b * OUTP + i];
                bs = fmaf(xx / (1.0f + expf(-xx)), bw5[i], bs);
            }
            v += wbv * bs;
        }
        out[b] = v;
    }
}

extern "C" void kernel_launch(void* const* d_in, const int* in_sizes, int n_in,
                              void* d_out, int out_size, void* d_ws, size_t ws_size,
                              hipStream_t stream)
{
    const float* x = (const float*)d_in[0];
    const float *bw[6], *sw[6], *wb[6], *ws[6];
    for (int l = 0; l < 6; ++l) {
        bw[l] = (const float*)d_in[1 + 4 * l];
        sw[l] = (const float*)d_in[2 + 4 * l];
        wb[l] = (const float*)d_in[3 + 4 * l];
        ws[l] = (const float*)d_in[4 + 4 * l];
    }
    // workspace layout (byte offsets)
    char* base = (char*)d_ws;
    const size_t PAIR_B = 0;                 // 243*102*256*4 = 25,380,864
    const size_t META_B = 25380864;          // 2048*243*16   =  7,962,624
    const size_t HA_B   = 33343488;          // 2048*256*4    =  2,097,152
    const size_t HB_B   = 35440640;          //                 2,097,152 -> end 37,537,792
    if (ws_size < (size_t)37537792) return;
    unsigned* pairT = (unsigned*)(base + PAIR_B);
    uint4*    meta  = (uint4*)(base + META_B);
    float*    hA    = (float*)(base + HA_B);
    float*    hB    = (float*)(base + HB_B);
    float*    outp  = (float*)d_out;

    const size_t HBYTES = (size_t)BATCH * OUTP * 4;

    // ---- layer 0: 64 -> 243, no residual ----
    pairgen_kernel<<<64, 256, 0, stream>>>(sw[0], 64, pairT);
    basis_kernel<64><<<(BATCH * 64) / 256, 256, 0, stream>>>(x, 64, meta);
    hipMemsetAsync(hA, 0, HBYTES, stream);
    layer_kernel<64, false><<<dim3(BATCH / 4, 4), 256, 0, stream>>>(
        pairT, meta, x, 64, bw[0], wb[0], ws[0], hA);

    // ---- layers 1..4: 243 -> 243, residual ----
    float* hin = hA; float* hout = hB;
    for (int l = 1; l <= 4; ++l) {
        pairgen_kernel<<<OUTR, 256, 0, stream>>>(sw[l], OUTR, pairT);
        basis_kernel<243><<<(BATCH * OUTR + 255) / 256, 256, 0, stream>>>(hin, OUTP, meta);
        hipMemsetAsync(hout, 0, HBYTES, stream);
        layer_kernel<243, true><<<dim3(BATCH / 4, 4), 256, 0, stream>>>(
            pairT, meta, hin, OUTP, bw[l], wb[l], ws[l], hout);
        float* tmp = hin; hin = hout; hout = tmp;
    }

    // ---- layer 5: 243 -> 1, no residual ----
    basis_kernel<243><<<(BATCH * OUTR + 255) / 256, 256, 0, stream>>>(hin, OUTP, meta);
    final_kernel<<<BATCH / 4, 256, 0, stream>>>(sw[5], meta, hin, bw[5], wb[5], ws[5], outp);
}